// Round 10
// baseline (294.221 us; speedup 1.0000x reference)
//
#include <hip/hip_runtime.h>
#include <math.h>

constexpr int Bn = 8, Cn = 512, Sn = 256, Mn = 200, Ln = 100;

// workspace layout (floats) — ~5.9 MB
constexpr size_t OFF_V    = 0;                                  // [B][C][S]
constexpr size_t OFF_ZNT  = OFF_V   + (size_t)Bn*Cn*Sn;         // [B][S][M] zn^T
constexpr size_t OFF_ZW   = OFF_ZNT + (size_t)Bn*Sn*Mn;         // [B][M] z.wsum
constexpr size_t OFF_ZPW  = OFF_ZW  + (size_t)Bn*Mn;            // [B][M] propagated.wsum
constexpr size_t OFF_WSUM = OFF_ZPW + (size_t)Bn*Mn;            // [S]
constexpr size_t OFF_CTR  = OFF_WSUM + Sn;                      // 512 uints (padded)
// done1[b] = ctr[b*32] ; done2[b] = ctr[256 + b*32]  (128B apart, no false sharing)

// ---------- vectorized block reductions (4 waves / 256 threads) ----------
template<int NW>
__device__ __forceinline__ float4 blk_max_f4(float4 x, float4* red) {
  #pragma unroll
  for (int o = 32; o; o >>= 1) {
    x.x = fmaxf(x.x, __shfl_xor(x.x, o));
    x.y = fmaxf(x.y, __shfl_xor(x.y, o));
    x.z = fmaxf(x.z, __shfl_xor(x.z, o));
    x.w = fmaxf(x.w, __shfl_xor(x.w, o));
  }
  __syncthreads();
  if ((threadIdx.x & 63) == 0) red[threadIdx.x >> 6] = x;
  __syncthreads();
  float4 r = red[0];
  #pragma unroll
  for (int w = 1; w < NW; ++w) {
    r.x = fmaxf(r.x, red[w].x); r.y = fmaxf(r.y, red[w].y);
    r.z = fmaxf(r.z, red[w].z); r.w = fmaxf(r.w, red[w].w);
  }
  return r;
}
template<int NW>
__device__ __forceinline__ float4 blk_sum_f4(float4 x, float4* red) {
  #pragma unroll
  for (int o = 32; o; o >>= 1) {
    x.x += __shfl_xor(x.x, o); x.y += __shfl_xor(x.y, o);
    x.z += __shfl_xor(x.z, o); x.w += __shfl_xor(x.w, o);
  }
  __syncthreads();
  if ((threadIdx.x & 63) == 0) red[threadIdx.x >> 6] = x;
  __syncthreads();
  float4 r = red[0];
  #pragma unroll
  for (int w = 1; w < NW; ++w) {
    r.x += red[w].x; r.y += red[w].y; r.z += red[w].z; r.w += red[w].w;
  }
  return r;
}

// ---------- D1: direct pool (no LDS): thread t owns output (i,jj), reads its
//              own 8x8 input block; 64B-sector-coalesced across the wave ----------
__global__ void __launch_bounds__(256) k_pool(const float* __restrict__ x,
                                              const float* __restrict__ ow,
                                              float* __restrict__ ws) {
  int t = threadIdx.x;
  if (blockIdx.x == 4096) {                  // wsum + zero spin counters
    unsigned* ctr = (unsigned*)(ws + OFF_CTR);
    ctr[t] = 0u; ctr[t + 256] = 0u;
    const float* row = ow + (size_t)t * Sn;
    float s = 0.f;
    for (int j = 0; j < Sn; j += 4) {
      float4 f = *(const float4*)(row + j);
      s += f.x + f.y + f.z + f.w;
    }
    ws[OFF_WSUM + t] = s;
    return;
  }
  int bc = blockIdx.x;                       // (b,c) plane, 0..4095
  int i = t >> 4, jj = t & 15;
  const float* base = x + (size_t)bc * 16384 + (size_t)(i * 8) * 128 + jj * 8;
  float s = 0.f;
  #pragma unroll
  for (int r = 0; r < 8; ++r) {
    float4 a = *(const float4*)(base + r * 128);
    float4 b = *(const float4*)(base + r * 128 + 4);
    s += a.x + a.y + a.z + a.w + b.x + b.y + b.z + b.w;
  }
  ws[OFF_V + (size_t)bc * 256 + t] = s * (1.0f / 64.0f);
}

// ---------- D2: 912 blocks, one dispatch, batch-scoped spin sync ----------
// blocks 0..399  : psz (t1=v.psi -> softmax_c -> z -> zn) -> [done1] -> gram -> [done2]
// blocks 400..911: P2 (t2=v.phi -> softmax_d, in LDS) -> wait done2 -> dot -> out
struct PszS { float pczl[4][256]; float As[4][512]; float zwl[200]; };
struct P2S  { float vl[8][256]; float t2l[16][104]; float zpl[200]; float vsl[8]; };
union MidS { PszS z; P2S p; };

__global__ void __launch_bounds__(256, 4)
k_mid(const float* __restrict__ psi, const float* __restrict__ phi,
      float* __restrict__ out, float* __restrict__ ws) {
  __shared__ MidS sh;
  __shared__ float4 red4[4];
  int bl = blockIdx.x, t = threadIdx.x;
  unsigned* ctr = (unsigned*)(ws + OFF_CTR);

  if (bl < 400) {
    // ================= psz =================
    int b = bl / 50, g = bl % 50, m0 = g * 4;
    const float* v = ws + OFF_V + (size_t)b * Cn * Sn;
    for (int e = t; e < 4 * 256; e += 256) {
      int mm = e >> 8, s = e & 255;
      int m = m0 + mm, k = m / Ln, d = m % Ln;
      sh.z.pczl[mm][s] = psi[(size_t)k * Sn * Ln + (size_t)s * Ln + d];
    }
    __syncthreads();
    // phase 1: thread t owns channels c = t and c = t+256
    float acc[2][4];
    #pragma unroll
    for (int mm = 0; mm < 4; ++mm) { acc[0][mm] = 0.f; acc[1][mm] = 0.f; }
    const float* vp0 = v + (size_t)t * Sn;
    const float* vp1 = v + (size_t)(t + 256) * Sn;
    for (int s = 0; s < Sn; s += 4) {
      float4 v0 = *(const float4*)(vp0 + s);
      float4 v1 = *(const float4*)(vp1 + s);
      #pragma unroll
      for (int mm = 0; mm < 4; ++mm) {
        float4 p = *(const float4*)&sh.z.pczl[mm][s];
        acc[0][mm] += v0.x * p.x + v0.y * p.y + v0.z * p.z + v0.w * p.w;
        acc[1][mm] += v1.x * p.x + v1.y * p.y + v1.z * p.z + v1.w * p.w;
      }
    }
    float4 a = make_float4(fmaxf(acc[0][0], acc[1][0]), fmaxf(acc[0][1], acc[1][1]),
                           fmaxf(acc[0][2], acc[1][2]), fmaxf(acc[0][3], acc[1][3]));
    float4 mx = blk_max_f4<4>(a, red4);
    float e00 = expf(acc[0][0] - mx.x), e10 = expf(acc[1][0] - mx.x);
    float e01 = expf(acc[0][1] - mx.y), e11 = expf(acc[1][1] - mx.y);
    float e02 = expf(acc[0][2] - mx.z), e12 = expf(acc[1][2] - mx.z);
    float e03 = expf(acc[0][3] - mx.w), e13 = expf(acc[1][3] - mx.w);
    float4 se = blk_sum_f4<4>(make_float4(e00 + e10, e01 + e11, e02 + e12, e03 + e13),
                              red4);
    sh.z.As[0][t] = e00 / se.x; sh.z.As[0][t + 256] = e10 / se.x;
    sh.z.As[1][t] = e01 / se.y; sh.z.As[1][t + 256] = e11 / se.y;
    sh.z.As[2][t] = e02 / se.z; sh.z.As[2][t + 256] = e12 / se.z;
    sh.z.As[3][t] = e03 / se.w; sh.z.As[3][t + 256] = e13 / se.w;
    __syncthreads();
    // phase 2: z[m, s=t]
    float zv[4] = {0, 0, 0, 0};
    for (int c = 0; c < Cn; c += 4) {
      float w0 = v[(size_t)(c + 0) * Sn + t];
      float w1 = v[(size_t)(c + 1) * Sn + t];
      float w2 = v[(size_t)(c + 2) * Sn + t];
      float w3 = v[(size_t)(c + 3) * Sn + t];
      #pragma unroll
      for (int mm = 0; mm < 4; ++mm) {
        float4 aa = *(const float4*)&sh.z.As[mm][c];
        zv[mm] += aa.x * w0 + aa.y * w1 + aa.z * w2 + aa.w * w3;
      }
    }
    float wsv = ws[OFF_WSUM + t];
    float4 n2 = blk_sum_f4<4>(make_float4(zv[0]*zv[0], zv[1]*zv[1],
                                          zv[2]*zv[2], zv[3]*zv[3]), red4);
    float4 zw = blk_sum_f4<4>(make_float4(zv[0]*wsv, zv[1]*wsv,
                                          zv[2]*wsv, zv[3]*wsv), red4);
    float zn0 = zv[0] * (1.0f / (sqrtf(n2.x) + 1e-6f));
    float zn1 = zv[1] * (1.0f / (sqrtf(n2.y) + 1e-6f));
    float zn2 = zv[2] * (1.0f / (sqrtf(n2.z) + 1e-6f));
    float zn3 = zv[3] * (1.0f / (sqrtf(n2.w) + 1e-6f));
    sh.z.pczl[0][t] = zn0; sh.z.pczl[1][t] = zn1;   // pc dead -> reuse as zl
    sh.z.pczl[2][t] = zn2; sh.z.pczl[3][t] = zn3;
    *(float4*)&ws[OFF_ZNT + ((size_t)b * Sn + t) * Mn + m0] =
        make_float4(zn0, zn1, zn2, zn3);
    if (t == 0) {
      float* zwp = ws + OFF_ZW + (size_t)b * Mn + m0;
      zwp[0] = zw.x; zwp[1] = zw.y; zwp[2] = zw.z; zwp[3] = zw.w;
    }
    __threadfence();                               // device-scope release
    if (t == 0) atomicAdd(&ctr[b * 32], 1u);
    // wait for all 50 psz groups of this batch (all 912 blocks co-resident)
    while (__hip_atomic_load(&ctr[b * 32], __ATOMIC_RELAXED,
                             __HIP_MEMORY_SCOPE_AGENT) < 50u)
      __builtin_amdgcn_s_sleep(16);
    __threadfence();                               // device-scope acquire
    for (int e = t; e < Mn; e += 256) sh.z.zwl[e] = ws[OFF_ZW + (size_t)b * Mn + e];
    __syncthreads();
    // ================= gram =================
    bool act = t < Mn;
    float dot[4] = {0, 0, 0, 0};
    if (act) {
      const float* zc = ws + OFF_ZNT + (size_t)b * Sn * Mn + t;  // column n=t
      for (int s = 0; s < Sn; s += 4) {
        float c0v = zc[(size_t)(s + 0) * Mn], c1v = zc[(size_t)(s + 1) * Mn];
        float c2v = zc[(size_t)(s + 2) * Mn], c3v = zc[(size_t)(s + 3) * Mn];
        #pragma unroll
        for (int mm = 0; mm < 4; ++mm) {
          float4 za = *(const float4*)&sh.z.pczl[mm][s];
          dot[mm] += za.x * c0v + za.y * c1v + za.z * c2v + za.w * c3v;
        }
      }
    }
    float4 e;                                      // |zn.zn| <= 1 -> no max-sub
    e.x = act ? expf(dot[0]) : 0.f;
    e.y = act ? expf(dot[1]) : 0.f;
    e.z = act ? expf(dot[2]) : 0.f;
    e.w = act ? expf(dot[3]) : 0.f;
    float4 seg = blk_sum_f4<4>(e, red4);
    float zwn = act ? sh.z.zwl[t] : 0.f;
    float4 sez = blk_sum_f4<4>(make_float4(e.x*zwn, e.y*zwn, e.z*zwn, e.w*zwn), red4);
    if (t == 0) {
      float* zp = ws + OFF_ZPW + (size_t)b * Mn + m0;
      zp[0] = sez.x / seg.x; zp[1] = sez.y / seg.y;
      zp[2] = sez.z / seg.z; zp[3] = sez.w / seg.w;
    }
    __threadfence();
    if (t == 0) atomicAdd(&ctr[256 + b * 32], 1u);
  } else {
    // ================= P2 (+ dot + out) =================
    int bl2 = bl - 400;
    int b = bl2 >> 6, cgrp = bl2 & 63, c0 = cgrp * 8;
    const float* v = ws + OFF_V + ((size_t)b * Cn + c0) * Sn;
    for (int e = t; e < 8 * 256; e += 256) {
      int cc = e >> 8, s = e & 255;
      sh.p.vl[cc][s] = v[(size_t)cc * Sn + s];
    }
    __syncthreads();
    int k = t >> 7, d = t & 127;
    int dd = d < Ln ? d : Ln - 1;
    const float* pp = phi + (size_t)k * Sn * Ln + dd;
    float acc[8] = {0, 0, 0, 0, 0, 0, 0, 0};
    for (int s = 0; s < Sn; s += 4) {
      float p0 = pp[(size_t)(s + 0) * Ln];
      float p1 = pp[(size_t)(s + 1) * Ln];
      float p2 = pp[(size_t)(s + 2) * Ln];
      float p3 = pp[(size_t)(s + 3) * Ln];
      #pragma unroll
      for (int cc = 0; cc < 8; ++cc) {
        float4 vv = *(const float4*)&sh.p.vl[cc][s];
        acc[cc] += vv.x * p0 + vv.y * p1 + vv.z * p2 + vv.w * p3;
      }
    }
    if (d < Ln) {
      #pragma unroll
      for (int cc = 0; cc < 8; ++cc) sh.p.t2l[k * 8 + cc][d] = acc[cc];
    }
    __syncthreads();
    // softmax_d per (k2, cc2) row, normalized IN LDS (P2 never leaves the block)
    int gg = t >> 4, l = t & 15;
    int k2 = gg >> 3, cc2 = gg & 7;
    float mxr = -1e30f;
    for (int dq = l; dq < Ln; dq += 16) mxr = fmaxf(mxr, sh.p.t2l[gg][dq]);
    #pragma unroll
    for (int o = 8; o; o >>= 1) mxr = fmaxf(mxr, __shfl_xor(mxr, o));
    float ser = 0.f;
    for (int dq = l; dq < Ln; dq += 16) ser += expf(sh.p.t2l[gg][dq] - mxr);
    #pragma unroll
    for (int o = 8; o; o >>= 1) ser += __shfl_xor(ser, o);
    for (int dq = l; dq < Ln; dq += 16)
      sh.p.t2l[gg][dq] = expf(sh.p.t2l[gg][dq] - mxr) / ser;
    if (k2 == 0) {                                 // vsum for this block's channels
      float vs = 0.f;
      for (int i2 = 0; i2 < 16; ++i2) vs += sh.p.vl[cc2][i2 * 16 + l];
      #pragma unroll
      for (int o = 8; o; o >>= 1) vs += __shfl_xor(vs, o);
      if (l == 0) sh.p.vsl[cc2] = vs;
    }
    __syncthreads();
    // wait for all 50 gram groups of this batch
    while (__hip_atomic_load(&ctr[256 + b * 32], __ATOMIC_RELAXED,
                             __HIP_MEMORY_SCOPE_AGENT) < 50u)
      __builtin_amdgcn_s_sleep(16);
    __threadfence();
    for (int e = t; e < Mn; e += 256) sh.p.zpl[e] = ws[OFF_ZPW + (size_t)b * Mn + e];
    __syncthreads();
    // dot + sigmoid: 32 lanes per channel
    int cc = t >> 5, l2 = t & 31;
    float accd = 0.f;
    for (int m = l2; m < Mn; m += 32)
      accd += sh.p.t2l[(m >= Ln ? 8 : 0) + cc][m >= Ln ? m - Ln : m] * sh.p.zpl[m];
    #pragma unroll
    for (int o = 16; o; o >>= 1) accd += __shfl_xor(accd, o);
    if (l2 == 0) {
      float f = (sh.p.vsl[cc] + accd) * (1.0f / 256.0f);
      out[(size_t)b * Cn + c0 + cc] = 1.0f / (1.0f + expf(-f));
    }
  }
}

extern "C" void kernel_launch(void* const* d_in, const int* in_sizes, int n_in,
                              void* d_out, int out_size, void* d_ws, size_t ws_size,
                              hipStream_t stream) {
  const float* x   = (const float*)d_in[0];
  const float* psi = (const float*)d_in[1];
  const float* phi = (const float*)d_in[2];
  const float* ow  = (const float*)d_in[3];
  float* out = (float*)d_out;
  float* ws  = (float*)d_ws;

  hipLaunchKernelGGL(k_pool, dim3(4097), dim3(256), 0, stream, x, ow, ws);
  hipLaunchKernelGGL(k_mid,  dim3(912),  dim3(256), 0, stream, psi, phi, out, ws);
}